// Round 12
// baseline (107.597 us; speedup 1.0000x reference)
//
#include <hip/hip_runtime.h>
#include <hip/hip_bf16.h>

#define B_SZ 256
#define L_SZ 50
#define N_SZ 100000
#define D_SZ 128
#define NCB 196                  // ceil(100000 / 512) col-blocks of 512
#define GEMM_BLOCKS (NCB * 8)    // x 8 row-groups of 32 rows

typedef __attribute__((ext_vector_type(8))) short bf16x8;
typedef __attribute__((ext_vector_type(4))) float f32x4;

__device__ inline unsigned short f2bf(float f) {
    union { float f; unsigned u; } v; v.f = f;
    unsigned r = v.u + 0x7FFFu + ((v.u >> 16) & 1u);   // round-to-nearest-even
    return (unsigned short)(r >> 16);
}

// ---------------- kernel 1: per-b, gather v, qW1/qW2, att, u -> bf16 frags (512 thr)
// Output u in MFMA FRAGMENT ORDER: for b-row b (rs=b>>4, lo=b&15) and dim d
// (ks=d>>5, hi=(d>>3)&3, j=d&7): u_fr[((ks*16+rs)*64 + hi*16+lo)*8 + j].
__global__ __launch_bounds__(512) void k_ub(const int* __restrict__ seeds,
                                            const float* __restrict__ E,
                                            const float* __restrict__ pe,
                                            const float* __restrict__ W1,
                                            const float* __restrict__ W2,
                                            const float* __restrict__ q,
                                            const float* __restrict__ b_att,
                                            unsigned short* __restrict__ u_fr,
                                            float* __restrict__ loss_slot) {
    __shared__ float vbuf[L_SZ][D_SZ + 1];
    __shared__ int   sseed[L_SZ];
    __shared__ float qs[D_SZ], qw1s[D_SZ], qw2s[D_SZ];
    __shared__ float part1[4][D_SZ], part2[4][D_SZ];
    __shared__ float att[L_SZ];
    __shared__ float c2s, qsums;
    int b = blockIdx.x, t = threadIdx.x;
    int g = t >> 7, d = t & 127;             // 4 groups x 128 threads

    if (t < L_SZ) sseed[t] = seeds[b * L_SZ + t];
    if (t < D_SZ) qs[t] = q[t];
    __syncthreads();

    #pragma unroll 4
    for (int l = g; l < L_SZ; l += 4)
        vbuf[l][d] = E[(size_t)sseed[l] * D_SZ + d] + pe[l * D_SZ + d];

    {
        float a1 = 0.f, a2 = 0.f;
        int e0 = g * 32;
        #pragma unroll 8
        for (int e = e0; e < e0 + 32; ++e) {
            float qe = qs[e];
            a1 += qe * W1[e * D_SZ + d];
            a2 += qe * W2[e * D_SZ + d];
        }
        part1[g][d] = a1;
        part2[g][d] = a2;
    }
    __syncthreads();
    if (t < D_SZ) {
        qw1s[t] = part1[0][t] + part1[1][t] + part1[2][t] + part1[3][t];
        qw2s[t] = part2[0][t] + part2[1][t] + part2[2][t] + part2[3][t];
    }
    __syncthreads();

    if (t < L_SZ * 8) {
        int l = t >> 3, sub = t & 7;
        float p = 0.f;
        #pragma unroll
        for (int k = sub * 16; k < sub * 16 + 16; ++k) p += vbuf[l][k] * qw1s[k];
        p += __shfl_xor(p, 1, 8);
        p += __shfl_xor(p, 2, 8);
        p += __shfl_xor(p, 4, 8);
        if (sub == 0) att[l] = p;
    } else if (t < L_SZ * 8 + 8) {
        int sub = t & 7;
        float p = 0.f;
        #pragma unroll
        for (int k = sub * 16; k < sub * 16 + 16; ++k) p += vbuf[L_SZ - 1][k] * qw2s[k];
        p += __shfl_xor(p, 1, 8);
        p += __shfl_xor(p, 2, 8);
        p += __shfl_xor(p, 4, 8);
        if (sub == 0) c2s = p;
    } else if (t < L_SZ * 8 + 16) {
        int sub = t & 7;
        float p = 0.f;
        #pragma unroll
        for (int k = sub * 16; k < sub * 16 + 16; ++k) p += qs[k];
        p += __shfl_xor(p, 1, 8);
        p += __shfl_xor(p, 2, 8);
        p += __shfl_xor(p, 4, 8);
        if (sub == 0) qsums = p;
    }
    __syncthreads();

    float add = c2s + b_att[0] * qsums;
    float up = 0.f;
    #pragma unroll 4
    for (int l = g; l < L_SZ; l += 4) up += (att[l] + add) * vbuf[l][d];
    __syncthreads();
    part1[g][d] = up;
    __syncthreads();
    if (t < D_SZ) {
        float uval = part1[0][t] + part1[1][t] + part1[2][t] + part1[3][t];
        int rs = b >> 4, lo = b & 15;
        int ks = t >> 5, hi = (t >> 3) & 3, j = t & 7;
        u_fr[(size_t)((ks * 16 + rs) * 64 + hi * 16 + lo) * 8 + j] = f2bf(uval);
    }

    if (b == 0 && t == 0) loss_slot[0] = 0.f;
}

// ---------------- kernel 2: scores = u @ E^T + bias (bf16 MFMA, long write runs)
// Block = 32 b-rows x 512 cols: cb=bid>>3 (col-block), rg=bid&7 (row-group).
// Wave wv: cols cb*512+wv*128..+128 as 8 sequential 16-col frags -> each row's
// writes are 512B SEQUENTIAL per wave (2KB per block) instead of 64-256B
// scattered. u-frags (32 rows) live in 8 regs, loaded once; no LDS staging,
// no barriers, no LDS atomics in the hot loop; per-lane running exp-sums.
// D layout per frag: lane (hi,lo): b-row rg*32+rs_l*16+lo, cols nc+hi*4..+3.
__global__ __launch_bounds__(256, 4) void k_gemm(const float* __restrict__ E,
                                                 const float* __restrict__ out_bias,
                                                 const unsigned short* __restrict__ u_fr,
                                                 float* __restrict__ scores,
                                                 float* __restrict__ partial) {
    __shared__ float lds_sum[32];
    int tid = threadIdx.x;
    int wv = tid >> 6, lane = tid & 63;
    int cb = blockIdx.x >> 3, rg = blockIdx.x & 7;
    int lo = lane & 15, hi = lane >> 4;
    int kb = hi * 8;
    if (tid < 32) lds_sum[tid] = 0.f;
    __syncthreads();

    // B-frags for this row-group's 32 rows (fragment-ordered u), loaded once
    bf16x8 bfr[2][4];                            // [rs_l][ks]
    #pragma unroll
    for (int rs = 0; rs < 2; ++rs)
        #pragma unroll
        for (int ks = 0; ks < 4; ++ks)
            bfr[rs][ks] = *(const bf16x8*)(u_fr + (size_t)((ks * 16 + rg * 2 + rs) * 64 + lane) * 8);

    int col0 = cb * 512 + wv * 128;
    int jr0 = rg * 32 + lo, jr1 = jr0 + 16;
    float esum0 = 0.f, esum1 = 0.f;

    #pragma unroll 2
    for (int f = 0; f < 8; ++f) {
        int nc = col0 + f * 16;
        if (nc < N_SZ) {                         // wave-uniform (N_SZ % 16 == 0)
            // E frags: 16 rows nc+lo, f32 -> bf16
            long erow = nc + lo;
            bf16x8 efrag[4];
            #pragma unroll
            for (int ks = 0; ks < 4; ++ks) {
                const float* p = E + (size_t)erow * D_SZ + ks * 32 + kb;
                float4 x = *(const float4*)p;
                float4 y = *(const float4*)(p + 4);
                bf16x8 fe;
                fe[0] = (short)f2bf(x.x); fe[1] = (short)f2bf(x.y);
                fe[2] = (short)f2bf(x.z); fe[3] = (short)f2bf(x.w);
                fe[4] = (short)f2bf(y.x); fe[5] = (short)f2bf(y.y);
                fe[6] = (short)f2bf(y.z); fe[7] = (short)f2bf(y.w);
                efrag[ks] = fe;
            }
            int nb = nc + hi * 4;
            float4 bias4 = *(const float4*)(out_bias + nb);

            f32x4 acc0 = (f32x4){0.f, 0.f, 0.f, 0.f};
            f32x4 acc1 = (f32x4){0.f, 0.f, 0.f, 0.f};
            #pragma unroll
            for (int ks = 0; ks < 4; ++ks) {
                acc0 = __builtin_amdgcn_mfma_f32_16x16x32_bf16(efrag[ks], bfr[0][ks], acc0, 0, 0, 0);
                acc1 = __builtin_amdgcn_mfma_f32_16x16x32_bf16(efrag[ks], bfr[1][ks], acc1, 0, 0, 0);
            }
            f32x4 c0, c1;
            c0[0] = acc0[0] + bias4.x; c0[1] = acc0[1] + bias4.y;
            c0[2] = acc0[2] + bias4.z; c0[3] = acc0[3] + bias4.w;
            c1[0] = acc1[0] + bias4.x; c1[1] = acc1[1] + bias4.y;
            c1[2] = acc1[2] + bias4.z; c1[3] = acc1[3] + bias4.w;
            *(f32x4*)(scores + (size_t)jr0 * N_SZ + nb) = c0;
            *(f32x4*)(scores + (size_t)jr1 * N_SZ + nb) = c1;
            esum0 += __expf(c0[0]) + __expf(c0[1]) + __expf(c0[2]) + __expf(c0[3]);
            esum1 += __expf(c1[0]) + __expf(c1[1]) + __expf(c1[2]) + __expf(c1[3]);
        }
    }

    // reduce esum over hi-groups (lanes {l, l^16, l^32, l^48} share the row)
    esum0 += __shfl_xor(esum0, 16); esum0 += __shfl_xor(esum0, 32);
    esum1 += __shfl_xor(esum1, 16); esum1 += __shfl_xor(esum1, 32);
    if (hi == 0) {
        atomicAdd(&lds_sum[lo], esum0);
        atomicAdd(&lds_sum[16 + lo], esum1);
    }
    __syncthreads();
    if (tid < 32) partial[(size_t)blockIdx.x * 32 + tid] = lds_sum[tid];
}

// ---------------- kernel 3: per-row logsumexp + NLL mean
__global__ __launch_bounds__(256) void k_loss(const float* __restrict__ partial,
                                              const float* __restrict__ scores,
                                              const int* __restrict__ labels,
                                              float* __restrict__ out_loss) {
    int b = blockIdx.x, t = threadIdx.x;
    int rg = b >> 5, rl = b & 31;
    float acc = 0.f;
    for (int cb = t; cb < NCB; cb += 256) acc += partial[(size_t)(cb * 8 + rg) * 32 + rl];
    __shared__ float red[256];
    red[t] = acc;
    __syncthreads();
    for (int s = 128; s > 0; s >>= 1) {
        if (t < s) red[t] += red[t + s];
        __syncthreads();
    }
    if (t == 0) {
        int lab = labels[b];
        float val = scores[(size_t)b * N_SZ + lab] - logf(red[0]);
        atomicAdd(out_loss, -val * (1.0f / (float)B_SZ));
    }
}

extern "C" void kernel_launch(void* const* d_in, const int* in_sizes, int n_in,
                              void* d_out, int out_size, void* d_ws, size_t ws_size,
                              hipStream_t stream) {
    const int*   seeds    = (const int*)d_in[0];
    const int*   labels   = (const int*)d_in[1];
    const float* E        = (const float*)d_in[2];
    const float* W1       = (const float*)d_in[3];
    const float* W2       = (const float*)d_in[4];
    const float* q        = (const float*)d_in[5];
    const float* b_att    = (const float*)d_in[6];
    const float* out_bias = (const float*)d_in[7];
    const float* pe       = (const float*)d_in[8];

    float* scores = (float*)d_out;
    float* loss   = scores + (size_t)B_SZ * N_SZ;

    // ws layout: @2048 u_fr (64KB, fragment-ordered) | @67584 partial (1568*32*4 = 200KB)
    unsigned short* u_fr    = (unsigned short*)((char*)d_ws + 2048);
    float*          partial = (float*)((char*)d_ws + 67584);

    k_ub<<<B_SZ, 512, 0, stream>>>(seeds, E, pe, W1, W2, q, b_att, u_fr, loss);
    k_gemm<<<GEMM_BLOCKS, 256, 0, stream>>>(E, out_bias, u_fr, scores, partial);
    k_loss<<<B_SZ, 256, 0, stream>>>(partial, scores, labels, loss);
}

// Round 13
// 68.528 us; speedup vs baseline: 1.5701x; 1.5701x over previous
//
#include <hip/hip_runtime.h>
#include <hip/hip_bf16.h>

#define B_SZ 256
#define L_SZ 50
#define N_SZ 100000
#define D_SZ 128
#define NBT ((N_SZ + 63) / 64)   // 1563 col-tiles of 64

typedef __attribute__((ext_vector_type(8))) short bf16x8;
typedef __attribute__((ext_vector_type(4))) float f32x4;

__device__ inline unsigned short f2bf(float f) {
    union { float f; unsigned u; } v; v.f = f;
    unsigned r = v.u + 0x7FFFu + ((v.u >> 16) & 1u);   // round-to-nearest-even
    return (unsigned short)(r >> 16);
}

// ---------------- kernel 1: per-b, gather v, qW1/qW2, att, u -> bf16 (512 thr, fused prep)
__global__ __launch_bounds__(512) void k_ub(const int* __restrict__ seeds,
                                            const float* __restrict__ E,
                                            const float* __restrict__ pe,
                                            const float* __restrict__ W1,
                                            const float* __restrict__ W2,
                                            const float* __restrict__ q,
                                            const float* __restrict__ b_att,
                                            unsigned short* __restrict__ u_bf,
                                            float* __restrict__ loss_slot) {
    __shared__ float vbuf[L_SZ][D_SZ + 1];
    __shared__ int   sseed[L_SZ];
    __shared__ float qs[D_SZ], qw1s[D_SZ], qw2s[D_SZ];
    __shared__ float part1[4][D_SZ], part2[4][D_SZ];
    __shared__ float att[L_SZ];
    __shared__ float c2s, qsums;
    int b = blockIdx.x, t = threadIdx.x;
    int g = t >> 7, d = t & 127;             // 4 groups x 128 threads

    if (t < L_SZ) sseed[t] = seeds[b * L_SZ + t];
    if (t < D_SZ) qs[t] = q[t];
    __syncthreads();

    #pragma unroll 4
    for (int l = g; l < L_SZ; l += 4)
        vbuf[l][d] = E[(size_t)sseed[l] * D_SZ + d] + pe[l * D_SZ + d];

    {
        float a1 = 0.f, a2 = 0.f;
        int e0 = g * 32;
        #pragma unroll 8
        for (int e = e0; e < e0 + 32; ++e) {
            float qe = qs[e];
            a1 += qe * W1[e * D_SZ + d];
            a2 += qe * W2[e * D_SZ + d];
        }
        part1[g][d] = a1;
        part2[g][d] = a2;
    }
    __syncthreads();
    if (t < D_SZ) {
        qw1s[t] = part1[0][t] + part1[1][t] + part1[2][t] + part1[3][t];
        qw2s[t] = part2[0][t] + part2[1][t] + part2[2][t] + part2[3][t];
    }
    __syncthreads();

    if (t < L_SZ * 8) {
        int l = t >> 3, sub = t & 7;
        float p = 0.f;
        #pragma unroll
        for (int k = sub * 16; k < sub * 16 + 16; ++k) p += vbuf[l][k] * qw1s[k];
        p += __shfl_xor(p, 1, 8);
        p += __shfl_xor(p, 2, 8);
        p += __shfl_xor(p, 4, 8);
        if (sub == 0) att[l] = p;
    } else if (t < L_SZ * 8 + 8) {
        int sub = t & 7;
        float p = 0.f;
        #pragma unroll
        for (int k = sub * 16; k < sub * 16 + 16; ++k) p += vbuf[L_SZ - 1][k] * qw2s[k];
        p += __shfl_xor(p, 1, 8);
        p += __shfl_xor(p, 2, 8);
        p += __shfl_xor(p, 4, 8);
        if (sub == 0) c2s = p;
    } else if (t < L_SZ * 8 + 16) {
        int sub = t & 7;
        float p = 0.f;
        #pragma unroll
        for (int k = sub * 16; k < sub * 16 + 16; ++k) p += qs[k];
        p += __shfl_xor(p, 1, 8);
        p += __shfl_xor(p, 2, 8);
        p += __shfl_xor(p, 4, 8);
        if (sub == 0) qsums = p;
    }
    __syncthreads();

    float add = c2s + b_att[0] * qsums;
    float up = 0.f;
    #pragma unroll 4
    for (int l = g; l < L_SZ; l += 4) up += (att[l] + add) * vbuf[l][d];
    __syncthreads();
    part1[g][d] = up;
    __syncthreads();
    if (t < D_SZ)
        u_bf[b * D_SZ + t] = f2bf(part1[0][t] + part1[1][t] + part1[2][t] + part1[3][t]);

    if (b == 0 && t == 0) loss_slot[0] = 0.f;
}

// ---------------- kernel 2: scores = u @ E^T + bias (bf16 MFMA, LDS-transposed stores)
// grid 3126 = 1563 col-tiles x 2 row-halves (rg fastest -> pair shares E).
// 256 thr = 4 waves (wave = 16-col panel). u-half (32 KB) staged swizzled.
// MFMA results land in padded LDS tile outT[128][68] f32; a linear store pass
// then writes each row's 256 B CONTIGUOUSLY (4 rows per wave-instr) -> long
// DRAM bursts instead of 64B/row scatter. exp/esum computed in the store pass.
__global__ __launch_bounds__(256, 4) void k_gemm(const float* __restrict__ E,
                                                 const float* __restrict__ out_bias,
                                                 const unsigned short* __restrict__ u_bf,
                                                 float* __restrict__ scores,
                                                 float* __restrict__ partial) {
    __shared__ unsigned short us[128 * D_SZ];    // 32 KB swizzled u-half
    __shared__ float outT[128][68];              // 34 KB padded output tile
    __shared__ float lds_sum[128];
    int tid = threadIdx.x;
    int w = tid >> 6, lane = tid & 63;
    int ct = blockIdx.x >> 1, rg = blockIdx.x & 1;
    int lo = lane & 15, hi = lane >> 4;
    int kb = hi * 8;
    if (tid < 128) lds_sum[tid] = 0.f;

    // ---- stage u-half: coalesced reads, swizzled LDS writes (byte ^= (row&7)<<4)
    const char* ub = (const char*)u_bf + rg * 32768;
    #pragma unroll
    for (int r = 0; r < 8; ++r) {
        int off = r * 4096 + tid * 16;
        int brow = off >> 8, inrow = off & 255;
        bf16x8 v = *(const bf16x8*)(ub + off);
        *(bf16x8*)((char*)us + brow * 256 + (inrow ^ ((brow & 7) << 4))) = v;
    }

    int nc = ct * 64 + w * 16;                   // this wave's 16-col panel
    bool valid = (nc < N_SZ);                    // wave-uniform (N_SZ % 16 == 0)

    // ---- A fragments: E rows (= score cols), f32 -> bf16 in regs
    bf16x8 efrag[4];
    if (valid) {
        long erow = nc + lo;
        #pragma unroll
        for (int ks = 0; ks < 4; ++ks) {
            const float* p = E + (size_t)erow * D_SZ + ks * 32 + kb;
            float4 x = *(const float4*)p;
            float4 y = *(const float4*)(p + 4);
            bf16x8 f;
            f[0] = (short)f2bf(x.x); f[1] = (short)f2bf(x.y);
            f[2] = (short)f2bf(x.z); f[3] = (short)f2bf(x.w);
            f[4] = (short)f2bf(y.x); f[5] = (short)f2bf(y.y);
            f[6] = (short)f2bf(y.z); f[7] = (short)f2bf(y.w);
            efrag[ks] = f;
        }
    }
    int nb = valid ? (nc + hi * 4) : 0;
    float4 bias4 = *(const float4*)(out_bias + nb);

    __syncthreads();                             // u staged; lds_sum zeroed

    if (valid) {
        f32x4 acc[8];
        #pragma unroll
        for (int i = 0; i < 8; ++i) acc[i] = (f32x4){0.f, 0.f, 0.f, 0.f};

        #pragma unroll
        for (int ks = 0; ks < 4; ++ks) {
            int kcol = ks * 64 + hi * 16;        // byte offset of 16B k-chunk
            #pragma unroll
            for (int rs = 0; rs < 8; ++rs) {
                int brow = rs * 16 + lo;
                bf16x8 uf = *(const bf16x8*)((const char*)us + brow * 256 + (kcol ^ ((brow & 7) << 4)));
                acc[rs] = __builtin_amdgcn_mfma_f32_16x16x32_bf16(efrag[ks], uf, acc[rs], 0, 0, 0);
            }
        }

        // scatter into LDS tile (2-way bank aliasing max with +4 pad)
        #pragma unroll
        for (int rs = 0; rs < 8; ++rs) {
            f32x4 c;
            c[0] = acc[rs][0] + bias4.x;
            c[1] = acc[rs][1] + bias4.y;
            c[2] = acc[rs][2] + bias4.z;
            c[3] = acc[rs][3] + bias4.w;
            *(f32x4*)&outT[rs * 16 + lo][w * 16 + hi * 4] = c;
        }
    }
    __syncthreads();

    // ---- linear store pass: 8 passes x 256 thr x 16B; lanes 0..15 = one row
    // -> each wave-instr writes 4 rows x 256B contiguous runs.
    #pragma unroll
    for (int p = 0; p < 8; ++p) {
        int idx = p * 256 + tid;
        int row = idx >> 4, c = idx & 15;
        int col = ct * 64 + c * 4;
        float s = 0.f;
        if (col < N_SZ) {
            f32x4 v = *(f32x4*)&outT[row][c * 4];
            *(f32x4*)(scores + (size_t)(rg * 128 + row) * N_SZ + col) = v;
            s = __expf(v[0]) + __expf(v[1]) + __expf(v[2]) + __expf(v[3]);
        }
        s += __shfl_xor(s, 1, 16);
        s += __shfl_xor(s, 2, 16);
        s += __shfl_xor(s, 4, 16);
        s += __shfl_xor(s, 8, 16);
        if ((tid & 15) == 0) atomicAdd(&lds_sum[row], s);
    }
    __syncthreads();
    if (tid < 128) partial[(size_t)blockIdx.x * 128 + tid] = lds_sum[tid];
}

// ---------------- kernel 3: per-row logsumexp + NLL mean
__global__ __launch_bounds__(256) void k_loss(const float* __restrict__ partial,
                                              const float* __restrict__ scores,
                                              const int* __restrict__ labels,
                                              float* __restrict__ out_loss) {
    int b = blockIdx.x, t = threadIdx.x;
    int rg = b >> 7, rl = b & 127;
    float acc = 0.f;
    for (int ctl = t; ctl < NBT; ctl += 256) acc += partial[(size_t)(ctl * 2 + rg) * 128 + rl];
    __shared__ float red[256];
    red[t] = acc;
    __syncthreads();
    for (int s = 128; s > 0; s >>= 1) {
        if (t < s) red[t] += red[t + s];
        __syncthreads();
    }
    if (t == 0) {
        int lab = labels[b];
        float val = scores[(size_t)b * N_SZ + lab] - logf(red[0]);
        atomicAdd(out_loss, -val * (1.0f / (float)B_SZ));
    }
}

extern "C" void kernel_launch(void* const* d_in, const int* in_sizes, int n_in,
                              void* d_out, int out_size, void* d_ws, size_t ws_size,
                              hipStream_t stream) {
    const int*   seeds    = (const int*)d_in[0];
    const int*   labels   = (const int*)d_in[1];
    const float* E        = (const float*)d_in[2];
    const float* W1       = (const float*)d_in[3];
    const float* W2       = (const float*)d_in[4];
    const float* q        = (const float*)d_in[5];
    const float* b_att    = (const float*)d_in[6];
    const float* out_bias = (const float*)d_in[7];
    const float* pe       = (const float*)d_in[8];

    float* scores = (float*)d_out;
    float* loss   = scores + (size_t)B_SZ * N_SZ;

    // ws layout: @2048 u_bf16 (64KB) | @67584 partial (3126*128*4 = 1.6MB)
    unsigned short* u_bf    = (unsigned short*)((char*)d_ws + 2048);
    float*          partial = (float*)((char*)d_ws + 67584);

    k_ub<<<B_SZ, 512, 0, stream>>>(seeds, E, pe, W1, W2, q, b_att, u_bf, loss);
    k_gemm<<<NBT * 2, 256, 0, stream>>>(E, out_bias, u_bf, scores, partial);
    k_loss<<<B_SZ, 256, 0, stream>>>(partial, scores, labels, loss);
}

// Round 14
// 56.987 us; speedup vs baseline: 1.8881x; 1.2025x over previous
//
#include <hip/hip_runtime.h>
#include <hip/hip_bf16.h>

#define B_SZ 256
#define L_SZ 50
#define N_SZ 100000
#define D_SZ 128
#define NB ((N_SZ + 127) / 128)   // 782 col-tiles of 128

typedef __attribute__((ext_vector_type(8))) short bf16x8;
typedef __attribute__((ext_vector_type(4))) float f32x4;

__device__ inline unsigned short f2bf(float f) {
    union { float f; unsigned u; } v; v.f = f;
    unsigned r = v.u + 0x7FFFu + ((v.u >> 16) & 1u);   // round-to-nearest-even
    return (unsigned short)(r >> 16);
}

// ---------------- kernel 1: per-b, gather v, qW1/qW2, att, u -> bf16 (512 thr, fused prep)
__global__ __launch_bounds__(512) void k_ub(const int* __restrict__ seeds,
                                            const float* __restrict__ E,
                                            const float* __restrict__ pe,
                                            const float* __restrict__ W1,
                                            const float* __restrict__ W2,
                                            const float* __restrict__ q,
                                            const float* __restrict__ b_att,
                                            unsigned short* __restrict__ u_bf,
                                            float* __restrict__ loss_slot) {
    __shared__ float vbuf[L_SZ][D_SZ + 1];
    __shared__ int   sseed[L_SZ];
    __shared__ float qs[D_SZ], qw1s[D_SZ], qw2s[D_SZ];
    __shared__ float part1[4][D_SZ], part2[4][D_SZ];
    __shared__ float att[L_SZ];
    __shared__ float c2s, qsums;
    int b = blockIdx.x, t = threadIdx.x;
    int g = t >> 7, d = t & 127;             // 4 groups x 128 threads

    if (t < L_SZ) sseed[t] = seeds[b * L_SZ + t];
    if (t < D_SZ) qs[t] = q[t];
    __syncthreads();

    // gather: group g handles rows l = g, g+4, ... (independent -> ILP)
    #pragma unroll 4
    for (int l = g; l < L_SZ; l += 4)
        vbuf[l][d] = E[(size_t)sseed[l] * D_SZ + d] + pe[l * D_SZ + d];

    // qW1/qW2: group g sums e in [g*32, g*32+32)
    {
        float a1 = 0.f, a2 = 0.f;
        int e0 = g * 32;
        #pragma unroll 8
        for (int e = e0; e < e0 + 32; ++e) {
            float qe = qs[e];
            a1 += qe * W1[e * D_SZ + d];
            a2 += qe * W2[e * D_SZ + d];
        }
        part1[g][d] = a1;
        part2[g][d] = a2;
    }
    __syncthreads();
    if (t < D_SZ) {
        qw1s[t] = part1[0][t] + part1[1][t] + part1[2][t] + part1[3][t];
        qw2s[t] = part2[0][t] + part2[1][t] + part2[2][t] + part2[3][t];
    }
    __syncthreads();

    // att[l] = vbuf[l,:] . qw1  — 8 lanes per row, shuffle-reduce (width 8)
    if (t < L_SZ * 8) {
        int l = t >> 3, sub = t & 7;
        float p = 0.f;
        #pragma unroll
        for (int k = sub * 16; k < sub * 16 + 16; ++k) p += vbuf[l][k] * qw1s[k];
        p += __shfl_xor(p, 1, 8);
        p += __shfl_xor(p, 2, 8);
        p += __shfl_xor(p, 4, 8);
        if (sub == 0) att[l] = p;
    } else if (t < L_SZ * 8 + 8) {           // c2 = vn . qw2
        int sub = t & 7;
        float p = 0.f;
        #pragma unroll
        for (int k = sub * 16; k < sub * 16 + 16; ++k) p += vbuf[L_SZ - 1][k] * qw2s[k];
        p += __shfl_xor(p, 1, 8);
        p += __shfl_xor(p, 2, 8);
        p += __shfl_xor(p, 4, 8);
        if (sub == 0) c2s = p;
    } else if (t < L_SZ * 8 + 16) {          // qsum
        int sub = t & 7;
        float p = 0.f;
        #pragma unroll
        for (int k = sub * 16; k < sub * 16 + 16; ++k) p += qs[k];
        p += __shfl_xor(p, 1, 8);
        p += __shfl_xor(p, 2, 8);
        p += __shfl_xor(p, 4, 8);
        if (sub == 0) qsums = p;
    }
    __syncthreads();

    // u[d] = sum_l (att[l]+add) * vbuf[l][d], l split over 4 groups
    float add = c2s + b_att[0] * qsums;
    float up = 0.f;
    #pragma unroll 4
    for (int l = g; l < L_SZ; l += 4) up += (att[l] + add) * vbuf[l][d];
    __syncthreads();                          // part1 free for reuse
    part1[g][d] = up;
    __syncthreads();
    if (t < D_SZ)
        u_bf[b * D_SZ + t] = f2bf(part1[0][t] + part1[1][t] + part1[2][t] + part1[3][t]);

    if (b == 0 && t == 0) loss_slot[0] = 0.f;
}

// ---------------- kernel 2: scores = u @ E^T + bias (bf16 MFMA)
// R4 structure (512 thr, 128 n-cols x 256 b-rows, full-u 64 KB swizzled LDS),
// epilogue interleaved: 4 groups of 4 rs, each group's stores+exp issued right
// after its MFMAs. E read exactly once, blocks in dispatch order.
// D layout: row=(lane>>4)*4+g -> n, col=lane&15 -> b => 16B stores per lane.
__global__ __launch_bounds__(512, 4) void k_gemm(const float* __restrict__ E,
                                                 const float* __restrict__ out_bias,
                                                 const unsigned short* __restrict__ u_bf,
                                                 float* __restrict__ scores,
                                                 float* __restrict__ partial) {
    __shared__ unsigned short us[B_SZ * D_SZ];   // 64 KB swizzled u
    __shared__ float lds_sum[B_SZ];
    int tid = threadIdx.x;
    int w = tid >> 6, lane = tid & 63;
    if (tid < B_SZ) lds_sum[tid] = 0.f;

    // ---- stage u: coalesced 16B/thread global reads, swizzled LDS writes
    #pragma unroll
    for (int r = 0; r < 8; ++r) {
        int off = r * 8192 + tid * 16;           // flat byte offset into u_bf
        int brow = off >> 8, inrow = off & 255;
        bf16x8 v = *(const bf16x8*)((const char*)u_bf + off);
        *(bf16x8*)((char*)us + brow * 256 + (inrow ^ ((brow & 7) << 4))) = v;
    }

    int nc = blockIdx.x * 128 + w * 16;          // this wave's 16-col panel
    bool valid = (nc < N_SZ);                    // wave-uniform (N_SZ % 16 == 0)
    int lo = lane & 15, hi = lane >> 4;
    int kb = hi * 8;

    // ---- A fragments: E rows (= score cols), f32 -> bf16 in regs
    long erow = valid ? (nc + lo) : 0;
    bf16x8 efrag[4];
    #pragma unroll
    for (int ks = 0; ks < 4; ++ks) {
        const float* p = E + (size_t)erow * D_SZ + ks * 32 + kb;
        float4 x = *(const float4*)p;
        float4 y = *(const float4*)(p + 4);
        bf16x8 f;
        f[0] = (short)f2bf(x.x); f[1] = (short)f2bf(x.y);
        f[2] = (short)f2bf(x.z); f[3] = (short)f2bf(x.w);
        f[4] = (short)f2bf(y.x); f[5] = (short)f2bf(y.y);
        f[6] = (short)f2bf(y.z); f[7] = (short)f2bf(y.w);
        efrag[ks] = f;
    }
    int nb = valid ? (nc + hi * 4) : 0;          // this lane's 4 consecutive n
    float4 bias4 = *(const float4*)(out_bias + nb);

    __syncthreads();                             // u staged; lds_sum zeroed

    // ---- 4 groups of 4 rs: MFMA (ks-outer, ILP=4) then store+exp immediately
    #pragma unroll
    for (int grp = 0; grp < 4; ++grp) {
        f32x4 acc[4];
        #pragma unroll
        for (int i = 0; i < 4; ++i) acc[i] = (f32x4){0.f, 0.f, 0.f, 0.f};

        #pragma unroll
        for (int ks = 0; ks < 4; ++ks) {
            int kcol = ks * 64 + hi * 16;        // byte offset of 16B k-chunk
            #pragma unroll
            for (int r4 = 0; r4 < 4; ++r4) {
                int brow = (grp * 4 + r4) * 16 + lo;
                bf16x8 uf = *(const bf16x8*)((const char*)us + brow * 256 + (kcol ^ ((brow & 7) << 4)));
                acc[r4] = __builtin_amdgcn_mfma_f32_16x16x32_bf16(efrag[ks], uf, acc[r4], 0, 0, 0);
            }
        }

        #pragma unroll
        for (int r4 = 0; r4 < 4; ++r4) {
            int jr = (grp * 4 + r4) * 16 + lo;   // this lane's b-row
            f32x4 c;
            c[0] = acc[r4][0] + bias4.x;
            c[1] = acc[r4][1] + bias4.y;
            c[2] = acc[r4][2] + bias4.z;
            c[3] = acc[r4][3] + bias4.w;
            if (valid)
                *(f32x4*)(scores + (size_t)jr * N_SZ + nb) = c;
            float p = __expf(c[0]) + __expf(c[1]) + __expf(c[2]) + __expf(c[3]);
            p += __shfl_xor(p, 16);
            p += __shfl_xor(p, 32);              // lanes {l, l^16, l^32, l^48} share jr
            if (valid && hi == 0) atomicAdd(&lds_sum[jr], p);
        }
        __builtin_amdgcn_sched_barrier(0);       // keep stores inside their group
    }
    __syncthreads();
    if (tid < B_SZ) partial[(size_t)blockIdx.x * B_SZ + tid] = lds_sum[tid];
}

// ---------------- kernel 3: per-row logsumexp + NLL mean
__global__ __launch_bounds__(256) void k_loss(const float* __restrict__ partial,
                                              const float* __restrict__ scores,
                                              const int* __restrict__ labels,
                                              float* __restrict__ out_loss) {
    int b = blockIdx.x, t = threadIdx.x;
    float acc = 0.f;
    for (int i = t; i < NB; i += 256) acc += partial[(size_t)i * B_SZ + b];
    __shared__ float red[256];
    red[t] = acc;
    __syncthreads();
    for (int s = 128; s > 0; s >>= 1) {
        if (t < s) red[t] += red[t + s];
        __syncthreads();
    }
    if (t == 0) {
        int lab = labels[b];
        float val = scores[(size_t)b * N_SZ + lab] - logf(red[0]);
        atomicAdd(out_loss, -val * (1.0f / (float)B_SZ));
    }
}

extern "C" void kernel_launch(void* const* d_in, const int* in_sizes, int n_in,
                              void* d_out, int out_size, void* d_ws, size_t ws_size,
                              hipStream_t stream) {
    const int*   seeds    = (const int*)d_in[0];
    const int*   labels   = (const int*)d_in[1];
    const float* E        = (const float*)d_in[2];
    const float* W1       = (const float*)d_in[3];
    const float* W2       = (const float*)d_in[4];
    const float* q        = (const float*)d_in[5];
    const float* b_att    = (const float*)d_in[6];
    const float* out_bias = (const float*)d_in[7];
    const float* pe       = (const float*)d_in[8];

    float* scores = (float*)d_out;
    float* loss   = scores + (size_t)B_SZ * N_SZ;

    // ws layout: @2048 u_bf16 (64KB) | @67584 partial (782*256*4 = 800KB)
    unsigned short* u_bf    = (unsigned short*)((char*)d_ws + 2048);
    float*          partial = (float*)((char*)d_ws + 67584);

    k_ub<<<B_SZ, 512, 0, stream>>>(seeds, E, pe, W1, W2, q, b_att, u_bf, loss);
    k_gemm<<<NB, 512, 0, stream>>>(E, out_bias, u_bf, scores, partial);
    k_loss<<<B_SZ, 256, 0, stream>>>(partial, scores, labels, loss);
}